// Round 3
// baseline (705.185 us; speedup 1.0000x reference)
//
#include <hip/hip_runtime.h>
#include <hip/hip_bf16.h>

using bf16 = __hip_bfloat16;
typedef short bf16x8 __attribute__((ext_vector_type(8)));
typedef float f32x4  __attribute__((ext_vector_type(4)));
typedef unsigned short u16;

__device__ __forceinline__ float leakyf(float x) { return x >= 0.f ? x : 0.01f * x; }

__device__ __forceinline__ float b2f(u16 u) {
  union { unsigned int i; float f; } c; c.i = (unsigned int)u << 16; return c.f;
}
__device__ __forceinline__ u16 f2b(float f) {
  __hip_bfloat16 h = __float2bfloat16(f);
  return *reinterpret_cast<u16*>(&h);
}

typedef const __attribute__((address_space(1))) unsigned int* gp_t;
typedef __attribute__((address_space(3))) unsigned int* lp_t;
__device__ __forceinline__ void gload16(const void* g, void* l) {
  __builtin_amdgcn_global_load_lds((gp_t)g, (lp_t)l, 16, 0, 0);
}

// ---------------------------------------------------------------------------
// Pack MFMA weight tiles: fp32 [K][Nc] -> bf16 slices [sl][nt20][ch8][i16][j8]
// type0 W0 (pu_W1 K320 Nc640, sl = p*5+ks), type1 W1t (pu_W2 K640 Nc320,
// sl = ks 0..9), type2 W4 (c_W rows 0..319, K320 Nc320, sl = ks 0..4)
// ---------------------------------------------------------------------------
__global__ void pack_tiles(const float* __restrict__ pu1, const float* __restrict__ pu2,
                           const float* __restrict__ cw,
                           bf16* __restrict__ W0, bf16* __restrict__ W1t,
                           bf16* __restrict__ W4) {
  int job = blockIdx.y, type = job / 3, l = job % 3;
  int f = blockIdx.x * 256 + threadIdx.x;
  const float* s; bf16* d; int ld, nchunks;
  if (type == 0)      { nchunks = 25600; s = pu1 + (size_t)l * 204800; d = W0  + (size_t)l * 204800; ld = 640; }
  else if (type == 1) { nchunks = 25600; s = pu2 + (size_t)l * 204800; d = W1t + (size_t)l * 204800; ld = 320; }
  else                { nchunks = 12800; s = cw  + (size_t)l * 204800; d = W4  + (size_t)l * 102400; ld = 320; }
  if (f >= nchunks) return;
  int i  = f & 15;
  int ch = (f >> 4) & 7;
  int nt = (f >> 7) % 20;
  int sl = (f >> 7) / 20;
  int k, col;
  if (type == 0) { k = (sl % 5) * 64 + ch * 8; col = (sl / 5) * 320 + nt * 16 + i; }
  else           { k = sl * 64 + ch * 8;       col = nt * 16 + i; }
  bf16 v[8];
#pragma unroll
  for (int j = 0; j < 8; ++j)
    v[j] = __float2bfloat16(s[(size_t)(k + j) * ld + col]);
  *(bf16x8*)(d + (size_t)f * 8) = *(bf16x8*)v;
}

// ---------------------------------------------------------------------------
// Pack GEMV weights n-major: out[n][k] = src[k][n]  (bf16)
// jobs: 0-2 Wg1 (gu_W1 K320 N640) 3-5 Wg2 (gu_W2 K640 N320)
//       6-8 Wg3 (c_W rows 320.. K320 N320) 9 Wo1 (o_W1 K320 N640)
// ---------------------------------------------------------------------------
__global__ void pack_nmaj(const float* __restrict__ gu1, const float* __restrict__ gu2,
                          const float* __restrict__ cw, const float* __restrict__ ow1,
                          bf16* __restrict__ Wg1, bf16* __restrict__ Wg2,
                          bf16* __restrict__ Wg3, bf16* __restrict__ Wo1) {
  int job = blockIdx.y;
  int f = blockIdx.x * 256 + threadIdx.x;
  const float* s; bf16* d; int K, ld, nchunks, koff = 0;
  if (job < 3)       { int l = job;     K = 320; ld = 640; nchunks = 25600; s = gu1 + (size_t)l * 204800; d = Wg1 + (size_t)l * 204800; }
  else if (job < 6)  { int l = job - 3; K = 640; ld = 320; nchunks = 25600; s = gu2 + (size_t)l * 204800; d = Wg2 + (size_t)l * 204800; }
  else if (job < 9)  { int l = job - 6; K = 320; ld = 320; nchunks = 12800; s = cw  + (size_t)l * 204800; d = Wg3 + (size_t)l * 102400; koff = 320; }
  else               {                  K = 320; ld = 640; nchunks = 25600; s = ow1;                      d = Wo1; }
  if (f >= nchunks) return;
  int kc8 = K >> 3;
  int n = f / kc8, kc = f % kc8;
  bf16 v[8];
#pragma unroll
  for (int j = 0; j < 8; ++j)
    v[j] = __float2bfloat16(s[(size_t)(koff + kc * 8 + j) * ld + n]);
  *(bf16x8*)(d + (size_t)f * 8) = *(bf16x8*)v;
}

// ---------------------------------------------------------------------------
// Fused per-group network. Block = 1 group (128 rows). 512 thr = 8 waves (2r x 4c).
// Wave (r,wc): rows r*64..r*64+63, col tiles {wc+4t} (16 cols each).
// Frags: C-layout col=lane&15, row=(lane>>4)*4+v (m89-verified).
// Panes: [128 rows][64 k] bf16, XOR-swizzled (byte ^= (row&7)<<4), dbuf.
// W slices: [nt][ch][i][j] prepacked, staged linear via global_load_lds.
// ---------------------------------------------------------------------------
#define PWROW(vv, comp) { int row = rb + vv; \
  *(short*)((char*)p + row * 128 + (col2 ^ ((row & 7) << 4))) = (short)(fq.comp); }

__device__ __forceinline__ void paneWrite4(short* p, ushort4 f0, ushort4 f1,
                                           ushort4 f2, ushort4 f3,
                                           int r, int wc, int i16, int kg) {
  const int col2 = (wc * 16 + i16) * 2;
  { ushort4 fq = f0; int rb = r * 64 + 0  + kg * 4; PWROW(0, x) PWROW(1, y) PWROW(2, z) PWROW(3, w) }
  { ushort4 fq = f1; int rb = r * 64 + 16 + kg * 4; PWROW(0, x) PWROW(1, y) PWROW(2, z) PWROW(3, w) }
  { ushort4 fq = f2; int rb = r * 64 + 32 + kg * 4; PWROW(0, x) PWROW(1, y) PWROW(2, z) PWROW(3, w) }
  { ushort4 fq = f3; int rb = r * 64 + 48 + kg * 4; PWROW(0, x) PWROW(1, y) PWROW(2, z) PWROW(3, w) }
}

__device__ __forceinline__ void stageW(const bf16* src, short* dst, int wave, int lane) {
#pragma unroll
  for (int t = 0; t < 5; ++t) {
    int ci = (t * 8 + wave) * 64 + lane;
    gload16(src + (size_t)ci * 8, (char*)dst + (t * 8 + wave) * 1024);
  }
}

__device__ __forceinline__ void sliceMFMA(f32x4 (&acc)[4][5], const short* pn,
                                          const short* wb,
                                          int r, int wc, int i16, int kg) {
#pragma unroll
  for (int kk = 0; kk < 2; ++kk) {
    bf16x8 a[4];
#pragma unroll
    for (int m = 0; m < 4; ++m) {
      int row = r * 64 + m * 16 + i16;
      a[m] = *(const bf16x8*)((const char*)pn + row * 128 +
                              (((kk * 32 + kg * 8) * 2) ^ ((row & 7) << 4)));
    }
#pragma unroll
    for (int t = 0; t < 5; ++t) {
      bf16x8 b = *(const bf16x8*)((const char*)wb +
                                  (((wc + 4 * t) * 8 + kk * 4 + kg) << 8) + (i16 << 4));
#pragma unroll
      for (int m = 0; m < 4; ++m)
        acc[m][t] = __builtin_amdgcn_mfma_f32_16x16x32_bf16(a[m], b, acc[m][t], 0, 0, 0);
    }
  }
}

__device__ __forceinline__ float dotWrow(const bf16* __restrict__ w,
                                         const float* __restrict__ x, int K8) {
  float s = 0.f;
#pragma unroll 4
  for (int kb = 0; kb < K8; ++kb) {
    bf16x8 wv = *(const bf16x8*)(w + kb * 8);
#pragma unroll
    for (int u = 0; u < 8; ++u)
      s += b2f((u16)wv[u]) * x[kb * 8 + u];
  }
  return s;
}

__device__ __forceinline__ ushort4 pack4(float a, float b, float c, float d) {
  ushort4 u; u.x = f2b(a); u.y = f2b(b); u.z = f2b(c); u.w = f2b(d); return u;
}

__global__ __launch_bounds__(512, 2)
void fused_k(const int* __restrict__ words, const int* __restrict__ lengths,
             const float* __restrict__ embed,
             const bf16* __restrict__ W0, const bf16* __restrict__ W1t,
             const bf16* __restrict__ W4,
             const bf16* __restrict__ Wg1, const bf16* __restrict__ Wg2,
             const bf16* __restrict__ Wg3, const bf16* __restrict__ Wo1,
             const float* __restrict__ pb1, const float* __restrict__ pb2,
             const float* __restrict__ gb1, const float* __restrict__ gb2,
             const float* __restrict__ cb,  const float* __restrict__ ob1,
             const float* __restrict__ oW2, const float* __restrict__ ob2,
             const float* __restrict__ wsc, float* __restrict__ yout)
{
  __shared__ short pane[2][8192];    // 2 x 16KB A-slices [128][64] swizzled
  __shared__ short wbuf[2][20480];   // 2 x 40KB W slices
  __shared__ float embL[1664];
  __shared__ int   wrdL[640];
  __shared__ float mvec[320];
  __shared__ float tvec[640];
  __shared__ float gvec[320];
  __shared__ float redA[320];
  __shared__ float redB[320];
  __shared__ float redH[8];

  const int g    = blockIdx.x;
  const int tid  = threadIdx.x;
  const int wave = tid >> 6, lane = tid & 63;
  const int r    = wave >> 2, wc = wave & 3;
  const int i16  = lane & 15, kg = lane >> 4;
  const float invLen = 1.0f / (float)lengths[g];

  // ---- load embed table + this group's words ----
  for (int i = tid; i < 1664; i += 512) embL[i] = embed[i];
  { const int* ws = words + (size_t)g * 640;
    for (int i = tid; i < 640; i += 512) wrdL[i] = ws[i]; }
  __syncthreads();

  // ---- init out frags from embedding (C-frag layout) ----
  ushort4 outf[4][5];
#pragma unroll
  for (int m = 0; m < 4; ++m) {
    int row = r * 64 + m * 16 + kg * 4;
#pragma unroll
    for (int t = 0; t < 5; ++t) {
      int col = (wc + 4 * t) * 16 + i16;
      int w = col >> 6, e = col & 63;
      outf[m][t] = pack4(embL[wrdL[(row + 0) * 5 + w] * 64 + e],
                         embL[wrdL[(row + 1) * 5 + w] * 64 + e],
                         embL[wrdL[(row + 2) * 5 + w] * 64 + e],
                         embL[wrdL[(row + 3) * 5 + w] * 64 + e]);
    }
  }

  for (int l = 0; l < 3; ++l) {
    // ================= GEMM1: h1 = leaky(out @ pu_W1 + b1)  [128,640] =========
    ushort4 h1f[2][4][5];
#pragma unroll
    for (int p = 0; p < 2; ++p) {
      f32x4 acc[4][5];
#pragma unroll
      for (int m = 0; m < 4; ++m)
#pragma unroll
        for (int t = 0; t < 5; ++t) acc[m][t] = {0.f, 0.f, 0.f, 0.f};
      const bf16* wsrc = W0 + ((size_t)(l * 2 + p) * 5) * 20480;
      __syncthreads();                       // protect pane[0]/wbuf[0] reuse
      stageW(wsrc, wbuf[0], wave, lane);
      paneWrite4(pane[0], outf[0][0], outf[1][0], outf[2][0], outf[3][0], r, wc, i16, kg);
#pragma unroll
      for (int ks = 0; ks < 5; ++ks) {
        __syncthreads();                     // slice ks staged + pane ready
        if (ks < 4) {
          stageW(wsrc + (size_t)(ks + 1) * 20480, wbuf[(ks + 1) & 1], wave, lane);
          paneWrite4(pane[(ks + 1) & 1], outf[0][ks + 1], outf[1][ks + 1],
                     outf[2][ks + 1], outf[3][ks + 1], r, wc, i16, kg);
        }
        sliceMFMA(acc, pane[ks & 1], wbuf[ks & 1], r, wc, i16, kg);
      }
      // epilogue -> h1 bf16 frags
#pragma unroll
      for (int t = 0; t < 5; ++t) {
        int col = p * 320 + (wc + 4 * t) * 16 + i16;
        float bv = pb1[l * 640 + col];
#pragma unroll
        for (int m = 0; m < 4; ++m)
          h1f[p][m][t] = pack4(leakyf(acc[m][t][0] + bv), leakyf(acc[m][t][1] + bv),
                               leakyf(acc[m][t][2] + bv), leakyf(acc[m][t][3] + bv));
      }
    }

    // ================= GEMM2: h = leaky(h1 @ pu_W2 + b2)  [128,320] ===========
    ushort4 hf[4][5];
    {
      f32x4 acc[4][5];
#pragma unroll
      for (int m = 0; m < 4; ++m)
#pragma unroll
        for (int t = 0; t < 5; ++t) acc[m][t] = {0.f, 0.f, 0.f, 0.f};
      const bf16* wsrc = W1t + (size_t)l * 10 * 20480;
      __syncthreads();
      stageW(wsrc, wbuf[0], wave, lane);
      paneWrite4(pane[0], h1f[0][0][0], h1f[0][1][0], h1f[0][2][0], h1f[0][3][0], r, wc, i16, kg);
#pragma unroll
      for (int ks = 0; ks < 10; ++ks) {
        __syncthreads();
        if (ks < 9) {
          stageW(wsrc + (size_t)(ks + 1) * 20480, wbuf[(ks + 1) & 1], wave, lane);
          const int p2 = (ks + 1) / 5, t2 = (ks + 1) % 5;
          paneWrite4(pane[(ks + 1) & 1], h1f[p2][0][t2], h1f[p2][1][t2],
                     h1f[p2][2][t2], h1f[p2][3][t2], r, wc, i16, kg);
        }
        sliceMFMA(acc, pane[ks & 1], wbuf[ks & 1], r, wc, i16, kg);
      }
      __syncthreads();
      // epilogue -> h frags + column sums for segment mean
      float csum[5];
#pragma unroll
      for (int t = 0; t < 5; ++t) {
        int col = (wc + 4 * t) * 16 + i16;
        float bv = pb2[l * 320 + col];
        float v0 = leakyf(acc[0][t][0] + bv), v1 = leakyf(acc[0][t][1] + bv);
        float v2 = leakyf(acc[0][t][2] + bv), v3 = leakyf(acc[0][t][3] + bv);
        float cs = v0 + v1 + v2 + v3;
        hf[0][t] = pack4(v0, v1, v2, v3);
#pragma unroll
        for (int m = 1; m < 4; ++m) {
          float w0 = leakyf(acc[m][t][0] + bv), w1 = leakyf(acc[m][t][1] + bv);
          float w2 = leakyf(acc[m][t][2] + bv), w3 = leakyf(acc[m][t][3] + bv);
          cs += w0 + w1 + w2 + w3;
          hf[m][t] = pack4(w0, w1, w2, w3);
        }
        csum[t] = cs;
      }
#pragma unroll
      for (int t = 0; t < 5; ++t) {
        float s = csum[t];
        s += __shfl_xor(s, 16);
        s += __shfl_xor(s, 32);
        if (kg == 0) (r ? redB : redA)[(wc + 4 * t) * 16 + i16] = s;
      }
      __syncthreads();
      if (tid < 320) mvec[tid] = (redA[tid] + redB[tid]) * invLen;
      __syncthreads();
    }

    // ================= group MLP (GEMV, VALU) ================================
    // t1 = leaky(m @ gu_W1 + gb1)  [640]
    tvec[tid] = leakyf(dotWrow(Wg1 + ((size_t)l * 640 + tid) * 320, mvec, 40) +
                       gb1[l * 640 + tid]);
    if (tid < 128) {
      int j2 = 512 + tid;
      tvec[j2] = leakyf(dotWrow(Wg1 + ((size_t)l * 640 + j2) * 320, mvec, 40) +
                        gb1[l * 640 + j2]);
    }
    __syncthreads();
    // g = leaky(t1 @ gu_W2 + gb2)  [320]
    if (tid < 320)
      gvec[tid] = leakyf(dotWrow(Wg2 + ((size_t)l * 320 + tid) * 640, tvec, 80) +
                         gb2[l * 320 + tid]);
    __syncthreads();
    // gAddc = g @ c_W[320:] + c_b  [320]  (stored in tvec)
    if (tid < 320)
      tvec[tid] = dotWrow(Wg3 + ((size_t)l * 320 + tid) * 320, gvec, 40) +
                  cb[l * 320 + tid];
    __syncthreads();

    // ================= combine: out = leaky(h @ cW_top + gAddc) + out =========
    {
      f32x4 acc[4][5];
#pragma unroll
      for (int m = 0; m < 4; ++m)
#pragma unroll
        for (int t = 0; t < 5; ++t) acc[m][t] = {0.f, 0.f, 0.f, 0.f};
      const bf16* wsrc = W4 + (size_t)l * 5 * 20480;
      __syncthreads();
      stageW(wsrc, wbuf[0], wave, lane);
      paneWrite4(pane[0], hf[0][0], hf[1][0], hf[2][0], hf[3][0], r, wc, i16, kg);
#pragma unroll
      for (int ks = 0; ks < 5; ++ks) {
        __syncthreads();
        if (ks < 4) {
          stageW(wsrc + (size_t)(ks + 1) * 20480, wbuf[(ks + 1) & 1], wave, lane);
          paneWrite4(pane[(ks + 1) & 1], hf[0][ks + 1], hf[1][ks + 1],
                     hf[2][ks + 1], hf[3][ks + 1], r, wc, i16, kg);
        }
        sliceMFMA(acc, pane[ks & 1], wbuf[ks & 1], r, wc, i16, kg);
      }
      __syncthreads();
      float csum[5];
#pragma unroll
      for (int t = 0; t < 5; ++t) {
        int col = (wc + 4 * t) * 16 + i16;
        float ga = tvec[col];
        ushort4 ov = outf[0][t];
        float v0 = leakyf(acc[0][t][0] + ga) + b2f(ov.x);
        float v1 = leakyf(acc[0][t][1] + ga) + b2f(ov.y);
        float v2 = leakyf(acc[0][t][2] + ga) + b2f(ov.z);
        float v3 = leakyf(acc[0][t][3] + ga) + b2f(ov.w);
        outf[0][t] = pack4(v0, v1, v2, v3);
        float cs = v0 + v1 + v2 + v3;
#pragma unroll
        for (int m = 1; m < 4; ++m) {
          ushort4 om = outf[m][t];
          float w0 = leakyf(acc[m][t][0] + ga) + b2f(om.x);
          float w1 = leakyf(acc[m][t][1] + ga) + b2f(om.y);
          float w2 = leakyf(acc[m][t][2] + ga) + b2f(om.z);
          float w3 = leakyf(acc[m][t][3] + ga) + b2f(om.w);
          outf[m][t] = pack4(w0, w1, w2, w3);
          cs += w0 + w1 + w2 + w3;
        }
        csum[t] = cs;
      }
      // column mean of new out (used by next head; cheap, do every layer)
#pragma unroll
      for (int t = 0; t < 5; ++t) {
        float s = csum[t];
        s += __shfl_xor(s, 16);
        s += __shfl_xor(s, 32);
        if (kg == 0) (r ? redB : redA)[(wc + 4 * t) * 16 + i16] = s;
      }
      __syncthreads();
      if (tid < 320) mvec[tid] = (redA[tid] + redB[tid]) * invLen;
      __syncthreads();
    }
  }

  // ================= final head ============================================
  tvec[tid] = leakyf(dotWrow(Wo1 + (size_t)tid * 320, mvec, 40) + ob1[tid]);
  if (tid < 128) {
    int j2 = 512 + tid;
    tvec[j2] = leakyf(dotWrow(Wo1 + (size_t)j2 * 320, mvec, 40) + ob1[j2]);
  }
  __syncthreads();
  float part = tvec[tid] * oW2[tid] + (tid < 128 ? tvec[512 + tid] * oW2[512 + tid] : 0.f);
#pragma unroll
  for (int off = 32; off > 0; off >>= 1) part += __shfl_down(part, off);
  if (lane == 0) redH[wave] = part;
  __syncthreads();
  if (tid == 0) {
    float s = 0.f;
#pragma unroll
    for (int w = 0; w < 8; ++w) s += redH[w];
    float y = leakyf(s + ob2[0]);
    yout[g] = y + wsc[0] * log2f((float)lengths[g]);
  }
}

// ---------------------------------------------------------------------------
extern "C" void kernel_launch(void* const* d_in, const int* in_sizes, int n_in,
                              void* d_out, int out_size, void* d_ws, size_t ws_size,
                              hipStream_t stream) {
  const int*   words   = (const int*)  d_in[0];
  const int*   lengths = (const int*)  d_in[1];
  // d_in[2] seg2all: contiguous groups (repeat(arange(B),SEG)) -> group = row/128
  const float* embedw  = (const float*)d_in[3];
  const float* pu_W1   = (const float*)d_in[4];
  const float* pu_b1   = (const float*)d_in[5];
  const float* pu_W2   = (const float*)d_in[6];
  const float* pu_b2   = (const float*)d_in[7];
  const float* gu_W1   = (const float*)d_in[8];
  const float* gu_b1   = (const float*)d_in[9];
  const float* gu_W2   = (const float*)d_in[10];
  const float* gu_b2   = (const float*)d_in[11];
  const float* c_W     = (const float*)d_in[12];
  const float* c_b     = (const float*)d_in[13];
  const float* o_W1    = (const float*)d_in[14];
  const float* o_b1    = (const float*)d_in[15];
  const float* o_W2    = (const float*)d_in[16];
  const float* o_b2    = (const float*)d_in[17];
  const float* wscal   = (const float*)d_in[18];

  const int B = in_sizes[1];

  size_t off = 0;
  auto alloc = [&](size_t bytes) -> void* {
    void* p = (char*)d_ws + off;
    off += (bytes + 255) & ~(size_t)255;
    return p;
  };
  bf16* W0  = (bf16*)alloc(614400 * 2);   // [3][2][5][20480]
  bf16* W1t = (bf16*)alloc(614400 * 2);   // [3][10][20480]
  bf16* W4  = (bf16*)alloc(307200 * 2);   // [3][5][20480]
  bf16* Wg1 = (bf16*)alloc(614400 * 2);   // [3][640][320]
  bf16* Wg2 = (bf16*)alloc(614400 * 2);   // [3][320][640]
  bf16* Wg3 = (bf16*)alloc(307200 * 2);   // [3][320][320]
  bf16* Wo1 = (bf16*)alloc(204800 * 2);   // [640][320]

  pack_tiles<<<dim3(100, 9), 256, 0, stream>>>(pu_W1, pu_W2, c_W, W0, W1t, W4);
  pack_nmaj<<<dim3(100, 10), 256, 0, stream>>>(gu_W1, gu_W2, c_W, o_W1,
                                               Wg1, Wg2, Wg3, Wo1);
  fused_k<<<B, 512, 0, stream>>>(words, lengths, embedw, W0, W1t, W4,
                                 Wg1, Wg2, Wg3, Wo1,
                                 pu_b1, pu_b2, gu_b1, gu_b2, c_b, o_b1,
                                 o_W2, o_b2, wscal, (float*)d_out);
}